// Round 2
// baseline (345.210 us; speedup 1.0000x reference)
//
#include <hip/hip_runtime.h>
#include <stdint.h>

// Problem constants (from setup_inputs; harness always uses these)
#define BB   2
#define CC   32      // input channels
#define TT   64      // input T
#define HWH  4096    // H*W = 64*64
#define NN   512     // coords per batch
#define CFF  32      // feat channels
#define CHH  16      // projection channels
#define TOUT 400     // featT == orgt == 400
#define LL   (TOUT*NN)  // 204800

__device__ __forceinline__ void lerp_coeff(int to, int& i0, int& i1, float& w){
  const float step = (float)(63.0 / 399.0);   // matches python (T-1)/(out_t-1) in f32
  float pos = (float)to * step;
  i0 = (int)floorf(pos);
  if (i0 > TT - 1) i0 = TT - 1;
  i1 = i0 + 1; if (i1 > TT - 1) i1 = TT - 1;
  w = pos - (float)i0;
}

// ---------------- Kernel A: r[b][t][hw] = sum_c Wr[c]*x[b][c][t][hw] + br ----------------
__global__ __launch_bounds__(256) void k_r(const float* __restrict__ x, const float* __restrict__ Wr,
                                           const float* __restrict__ br, float* __restrict__ r){
  int tid = blockIdx.x * 256 + threadIdx.x;   // 131072 threads, 4 hw each
  int hw0 = (tid & 1023) << 2;
  int t   = (tid >> 10) & 63;
  int b   = tid >> 16;
  float br0 = br[0];
  float4 acc = make_float4(br0, br0, br0, br0);
  const float* xp = x + ((size_t)(b * CC) * TT + t) * HWH + hw0;
  #pragma unroll
  for (int c = 0; c < CC; ++c){
    float4 v = *reinterpret_cast<const float4*>(xp + (size_t)c * TT * HWH);
    float w = Wr[c];
    acc.x += w * v.x;  acc.y += w * v.y;  acc.z += w * v.z;  acc.w += w * v.w;
  }
  *reinterpret_cast<float4*>(r + ((size_t)(b * TT + t)) * HWH + hw0) = acc;
}

// ---------------- Kernel B: result = lerp_t(r) ----------------
__global__ __launch_bounds__(256) void k_result(const float* __restrict__ r, float* __restrict__ outR){
  int tid = blockIdx.x * 256 + threadIdx.x;   // 819200 threads, 4 hw each
  int hw0  = (tid & 1023) << 2;
  int rest = tid >> 10;                       // 0..799 = b*400+to
  int b  = rest >= TOUT ? 1 : 0;
  int to = rest - b * TOUT;
  int i0, i1; float w;
  lerp_coeff(to, i0, i1, w);
  float4 a = *reinterpret_cast<const float4*>(r + ((size_t)(b * TT + i0)) * HWH + hw0);
  float4 c = *reinterpret_cast<const float4*>(r + ((size_t)(b * TT + i1)) * HWH + hw0);
  float4 o;
  o.x = a.x + w * (c.x - a.x);
  o.y = a.y + w * (c.y - a.y);
  o.z = a.z + w * (c.z - a.z);
  o.w = a.w + w * (c.w - a.w);
  *reinterpret_cast<float4*>(outR + ((size_t)(b * TOUT + to)) * HWH + hw0) = o;
}

// ---------------- Kernel C: G[b][t][n][cf] = Wf . x[b,:,t,coord(b,n)] + bf ----------------
__global__ __launch_bounds__(256) void k_gather(const float* __restrict__ x, const int* __restrict__ coord,
                                                const float* __restrict__ Wf, const float* __restrict__ bfv,
                                                float* __restrict__ G){
  __shared__ float sWf[CFF][CC];
  __shared__ float sbf[CFF];
  for (int i = threadIdx.x; i < CFF * CC; i += 256) sWf[i >> 5][i & 31] = Wf[i];
  if (threadIdx.x < CFF) sbf[threadIdx.x] = bfv[threadIdx.x];
  __syncthreads();
  int tid = blockIdx.x * 256 + threadIdx.x;   // 65536 = (b,t,n)
  int n = tid & 511;
  int t = (tid >> 9) & 63;
  int b = tid >> 15;
  int h  = coord[((size_t)b * NN + n) * 2 + 0];
  int wq = coord[((size_t)b * NN + n) * 2 + 1];
  int hw = h * 64 + wq;
  float xv[CC];
  #pragma unroll
  for (int c = 0; c < CC; ++c)
    xv[c] = x[(((size_t)(b * CC + c)) * TT + t) * HWH + hw];
  float tmp[CFF];
  #pragma unroll
  for (int cf = 0; cf < CFF; ++cf){
    float a = sbf[cf];
    #pragma unroll
    for (int c = 0; c < CC; ++c) a += sWf[cf][c] * xv[c];
    tmp[cf] = a;
  }
  float* Gp = G + ((size_t)((b * TT + t) * NN + n)) * CFF;
  #pragma unroll
  for (int j = 0; j < CFF; j += 4)
    *reinterpret_cast<float4*>(Gp + j) = make_float4(tmp[j], tmp[j+1], tmp[j+2], tmp[j+3]);
}

// ---------------- Kernel D: BN stats (sum, sumsq of h per channel) ----------------
__global__ __launch_bounds__(256) void k_stats(const float* __restrict__ G, const float* __restrict__ W1,
                                               const float* __restrict__ b1, float* __restrict__ stats){
  __shared__ float sW1[CHH][CFF];
  __shared__ float sb1[CHH];
  __shared__ float red[4][32];
  for (int i = threadIdx.x; i < CHH * CFF; i += 256) sW1[i >> 5][i & 31] = W1[i];
  if (threadIdx.x < CHH) sb1[threadIdx.x] = b1[threadIdx.x];
  __syncthreads();
  // XCD-contiguous block swizzle: 200 blocks -> 8 XCDs x 25 contiguous
  int xcd = blockIdx.x & 7, loc = blockIdx.x >> 3;
  int eb = xcd * 25 + loc;
  float psum[CHH], psq[CHH];
  #pragma unroll
  for (int o = 0; o < CHH; ++o){ psum[o] = 0.f; psq[o] = 0.f; }
  for (int k = 0; k < 8; ++k){
    int li  = eb * 2048 + k * 256 + (int)threadIdx.x;  // 0..409599
    int b   = li / LL;
    int rem = li - b * LL;
    int to  = rem >> 9;
    int n   = rem & 511;
    int i0, i1; float w;
    lerp_coeff(to, i0, i1, w);
    const float* g0 = G + ((size_t)((b * TT + i0) * NN + n)) * CFF;
    const float* g1 = G + ((size_t)((b * TT + i1) * NN + n)) * CFF;
    float g[CFF];
    #pragma unroll
    for (int c = 0; c < CFF; c += 4){
      float4 a = *reinterpret_cast<const float4*>(g0 + c);
      float4 d = *reinterpret_cast<const float4*>(g1 + c);
      g[c]   = a.x + w * (d.x - a.x);
      g[c+1] = a.y + w * (d.y - a.y);
      g[c+2] = a.z + w * (d.z - a.z);
      g[c+3] = a.w + w * (d.w - a.w);
    }
    #pragma unroll
    for (int o = 0; o < CHH; ++o){
      float h = sb1[o];
      #pragma unroll
      for (int c = 0; c < CFF; ++c) h += sW1[o][c] * g[c];
      psum[o] += h;
      psq[o]  += h * h;
    }
  }
  #pragma unroll
  for (int o = 0; o < CHH; ++o){
    #pragma unroll
    for (int s = 32; s > 0; s >>= 1){
      psum[o] += __shfl_down(psum[o], s, 64);
      psq[o]  += __shfl_down(psq[o], s, 64);
    }
  }
  int wave = threadIdx.x >> 6, lane = threadIdx.x & 63;
  if (lane == 0){
    #pragma unroll
    for (int o = 0; o < CHH; ++o){ red[wave][o] = psum[o]; red[wave][16 + o] = psq[o]; }
  }
  __syncthreads();
  if (threadIdx.x < 32){
    float v = red[0][threadIdx.x] + red[1][threadIdx.x] + red[2][threadIdx.x] + red[3][threadIdx.x];
    atomicAdd(stats + threadIdx.x, v);
  }
}

// ---------------- Kernel D2: fold BN into scale/shift ----------------
__global__ void k_fin(const float* __restrict__ gamma, const float* __restrict__ beta, float* __restrict__ stats){
  int o = threadIdx.x;
  if (o < CHH){
    float inv = 1.0f / (float)(BB * (long long)LL);
    float mu  = stats[o] * inv;
    float var = stats[16 + o] * inv - mu * mu;
    float sc  = gamma[o] * (1.0f / sqrtf(var + 1e-5f));
    stats[32 + o] = sc;
    stats[48 + o] = beta[o] - mu * sc;
  }
}

// ---------------- Kernel E: h -> BN -> ReLU -> W2 -> out ----------------
__global__ __launch_bounds__(256) void k_out(const float* __restrict__ G, const float* __restrict__ W1,
                                             const float* __restrict__ b1, const float* __restrict__ W2,
                                             const float* __restrict__ b2, const float* __restrict__ stats,
                                             float* __restrict__ out){
  __shared__ float sW1[CHH][CFF];
  __shared__ float sW2[CHH][CHH];
  __shared__ float sb1[CHH], sb2[CHH], ssc[CHH], ssh[CHH];
  for (int i = threadIdx.x; i < CHH * CFF; i += 256) sW1[i >> 5][i & 31] = W1[i];
  for (int i = threadIdx.x; i < CHH * CHH; i += 256) sW2[i >> 4][i & 15] = W2[i];
  if (threadIdx.x < CHH){
    sb1[threadIdx.x] = b1[threadIdx.x];
    sb2[threadIdx.x] = b2[threadIdx.x];
    ssc[threadIdx.x] = stats[32 + threadIdx.x];
    ssh[threadIdx.x] = stats[48 + threadIdx.x];
  }
  __syncthreads();
  // XCD-contiguous block swizzle: 1600 blocks -> 8 XCDs x 200 contiguous (L2 reuse of G slabs)
  int xcd = blockIdx.x & 7, loc = blockIdx.x >> 3;
  int eb = xcd * 200 + loc;
  int li  = eb * 256 + (int)threadIdx.x;   // 0..409599
  int b   = li / LL;
  int rem = li - b * LL;
  int to  = rem >> 9;
  int n   = rem & 511;
  int i0, i1; float w;
  lerp_coeff(to, i0, i1, w);
  const float* g0 = G + ((size_t)((b * TT + i0) * NN + n)) * CFF;
  const float* g1 = G + ((size_t)((b * TT + i1) * NN + n)) * CFF;
  float g[CFF];
  #pragma unroll
  for (int c = 0; c < CFF; c += 4){
    float4 a = *reinterpret_cast<const float4*>(g0 + c);
    float4 d = *reinterpret_cast<const float4*>(g1 + c);
    g[c]   = a.x + w * (d.x - a.x);
    g[c+1] = a.y + w * (d.y - a.y);
    g[c+2] = a.z + w * (d.z - a.z);
    g[c+3] = a.w + w * (d.w - a.w);
  }
  float hr[CHH];
  #pragma unroll
  for (int o = 0; o < CHH; ++o){
    float h = sb1[o];
    #pragma unroll
    for (int c = 0; c < CFF; ++c) h += sW1[o][c] * g[c];
    hr[o] = fmaxf(h * ssc[o] + ssh[o], 0.0f);
  }
  #pragma unroll
  for (int o2 = 0; o2 < CHH; ++o2){
    float v = sb2[o2];
    #pragma unroll
    for (int o = 0; o < CHH; ++o) v += sW2[o2][o] * hr[o];
    out[((size_t)(b * CHH + o2)) * LL + rem] = v;
  }
}

extern "C" void kernel_launch(void* const* d_in, const int* in_sizes, int n_in,
                              void* d_out, int out_size, void* d_ws, size_t ws_size,
                              hipStream_t stream){
  (void)in_sizes; (void)n_in; (void)out_size; (void)ws_size;
  const float* x     = (const float*)d_in[0];
  const int*   coord = (const int*)d_in[1];
  const float* Wf    = (const float*)d_in[2];
  const float* bfv   = (const float*)d_in[3];
  const float* Wr    = (const float*)d_in[4];
  const float* br    = (const float*)d_in[5];
  const float* W1    = (const float*)d_in[6];
  const float* b1    = (const float*)d_in[7];
  const float* gamma = (const float*)d_in[8];
  const float* beta  = (const float*)d_in[9];
  const float* W2    = (const float*)d_in[10];
  const float* b2    = (const float*)d_in[11];

  float* ws    = (float*)d_ws;
  float* r     = ws;                          // 524288 f32  (2 MB)
  float* G     = ws + 524288;                 // 2097152 f32 (8 MB)
  float* stats = ws + 524288 + 2097152;       // 64 f32: [sum16, sumsq16, scale16, shift16]

  float* out  = (float*)d_out;                // [B,16,L] = 6,553,600 f32
  float* outR = out + (size_t)BB * CHH * LL;  // [B,1,400,64,64] = 3,276,800 f32

  hipMemsetAsync(stats, 0, 32 * sizeof(float), stream);
  k_r     <<<512,  256, 0, stream>>>(x, Wr, br, r);
  k_gather<<<256,  256, 0, stream>>>(x, coord, Wf, bfv, G);
  k_result<<<3200, 256, 0, stream>>>(r, outR);
  k_stats <<<200,  256, 0, stream>>>(G, W1, b1, stats);
  k_fin   <<<1,    64,  0, stream>>>(gamma, beta, stats);
  k_out   <<<1600, 256, 0, stream>>>(G, W1, b1, W2, b2, stats, out);
}

// Round 3
// 203.918 us; speedup vs baseline: 1.6929x; 1.6929x over previous
//
#include <hip/hip_runtime.h>
#include <stdint.h>

// Problem constants (from setup_inputs; harness always uses these)
#define BB   2
#define CC   32      // input channels
#define TT   64      // input T
#define HWH  4096    // H*W = 64*64
#define NN   512     // coords per batch
#define CFF  32      // feat channels
#define CHH  16      // projection channels
#define TOUT 400     // featT == orgt == 400
#define LL   (TOUT*NN)  // 204800

__device__ __forceinline__ void lerp_coeff(int to, int& i0, int& i1, float& w){
  const float step = (float)(63.0 / 399.0);   // matches python (T-1)/(out_t-1) in f32
  float pos = (float)to * step;
  i0 = (int)floorf(pos);
  if (i0 > TT - 1) i0 = TT - 1;
  i1 = i0 + 1; if (i1 > TT - 1) i1 = TT - 1;
  w = pos - (float)i0;
}

// ---------------- coefficient kernel: q_t, a_t, c_t over the 400 output steps ----------------
// coef[0..63]=q (linear weight), [64..127]=a (square weight), [128..191]=c (cross t,t+1)
__global__ void k_coef(float* __restrict__ coef){
  int to = blockIdx.x * 256 + threadIdx.x;
  if (to < TOUT){
    int i0, i1; float w;
    lerp_coeff(to, i0, i1, w);
    if (i1 == i0){                 // degenerate (pos lands on last node): value = y_t exactly
      atomicAdd(coef + i0, 1.f);
      atomicAdd(coef + 64 + i0, 1.f);
    } else {
      float u = 1.f - w;
      atomicAdd(coef + i0, u);        atomicAdd(coef + 64 + i0, u * u);
      atomicAdd(coef + i1, w);        atomicAdd(coef + 64 + i1, w * w);
      atomicAdd(coef + 128 + i0, 2.f * w * u);
    }
  }
}

// ---------------- Kernel A: r[b][t][hw] = sum_c Wr[c]*x[b][c][t][hw] + br ----------------
__global__ __launch_bounds__(256) void k_r(const float* __restrict__ x, const float* __restrict__ Wr,
                                           const float* __restrict__ br, float* __restrict__ r){
  int tid = blockIdx.x * 256 + threadIdx.x;   // 131072 threads, 4 hw each
  int hw0 = (tid & 1023) << 2;
  int t   = (tid >> 10) & 63;
  int b   = tid >> 16;
  float br0 = br[0];
  float4 acc = make_float4(br0, br0, br0, br0);
  const float* xp = x + ((size_t)(b * CC) * TT + t) * HWH + hw0;
  #pragma unroll
  for (int c = 0; c < CC; ++c){
    float4 v = *reinterpret_cast<const float4*>(xp + (size_t)c * TT * HWH);
    float w = Wr[c];
    acc.x += w * v.x;  acc.y += w * v.y;  acc.z += w * v.z;  acc.w += w * v.w;
  }
  *reinterpret_cast<float4*>(r + ((size_t)(b * TT + t)) * HWH + hw0) = acc;
}

// ---------------- Kernel B: result = lerp_t(r) ----------------
__global__ __launch_bounds__(256) void k_result(const float* __restrict__ r, float* __restrict__ outR){
  int tid = blockIdx.x * 256 + threadIdx.x;   // 819200 threads, 4 hw each
  int hw0  = (tid & 1023) << 2;
  int rest = tid >> 10;                       // 0..799 = b*400+to
  int b  = rest >= TOUT ? 1 : 0;
  int to = rest - b * TOUT;
  int i0, i1; float w;
  lerp_coeff(to, i0, i1, w);
  float4 a = *reinterpret_cast<const float4*>(r + ((size_t)(b * TT + i0)) * HWH + hw0);
  float4 c = *reinterpret_cast<const float4*>(r + ((size_t)(b * TT + i1)) * HWH + hw0);
  float4 o;
  o.x = a.x + w * (c.x - a.x);
  o.y = a.y + w * (c.y - a.y);
  o.z = a.z + w * (c.z - a.z);
  o.w = a.w + w * (c.w - a.w);
  *reinterpret_cast<float4*>(outR + ((size_t)(b * TOUT + to)) * HWH + hw0) = o;
}

// ---------------- Kernel C: G[b][t][n][cf] = Wf . x[b,:,t,coord(b,n)] + bf ----------------
// 4 lanes per element; each lane gathers 8 input channels, x shared via __shfl.
__global__ __launch_bounds__(256) void k_gather(const float* __restrict__ x, const int* __restrict__ coord,
                                                const float* __restrict__ Wf, const float* __restrict__ bfv,
                                                float* __restrict__ G){
  __shared__ float sWfT[CC][CFF];   // transposed: [c][cf] -> conflict-free float4 broadcast
  __shared__ float sbf[CFF];
  for (int i = threadIdx.x; i < CFF * CC; i += 256){
    int cf = i >> 5, c = i & 31;
    sWfT[c][cf] = Wf[i];
  }
  if (threadIdx.x < CFF) sbf[threadIdx.x] = bfv[threadIdx.x];
  __syncthreads();
  int lane = threadIdx.x & 63;
  int sub  = threadIdx.x & 3;                       // channel quarter
  int e = blockIdx.x * 64 + ((int)threadIdx.x >> 2); // element 0..65535 = (b,t,n)
  int n = e & 511, t = (e >> 9) & 63, b = e >> 15;
  int h  = coord[(b * NN + n) * 2 + 0];
  int wq = coord[(b * NN + n) * 2 + 1];
  int hw = h * 64 + wq;
  const float* xp = x + (((size_t)(b * CC + sub * 8)) * TT + t) * HWH + hw;
  float xv[8];
  #pragma unroll
  for (int j = 0; j < 8; ++j) xv[j] = xp[(size_t)j * (TT * HWH)];
  float acc[8];
  #pragma unroll
  for (int i = 0; i < 8; ++i) acc[i] = sbf[sub * 8 + i];
  int grp = lane & ~3;
  #pragma unroll
  for (int j = 0; j < 8; ++j){
    #pragma unroll
    for (int src = 0; src < 4; ++src){
      float xc = __shfl(xv[j], grp + src, 64);   // channel c = src*8+j of this element
      int c = src * 8 + j;
      const float4 wa = *reinterpret_cast<const float4*>(&sWfT[c][sub * 8]);
      const float4 wb = *reinterpret_cast<const float4*>(&sWfT[c][sub * 8 + 4]);
      acc[0] += wa.x * xc;  acc[1] += wa.y * xc;  acc[2] += wa.z * xc;  acc[3] += wa.w * xc;
      acc[4] += wb.x * xc;  acc[5] += wb.y * xc;  acc[6] += wb.z * xc;  acc[7] += wb.w * xc;
    }
  }
  float* Gp = G + ((size_t)((b * TT + t) * NN + n)) * CFF + sub * 8;
  *reinterpret_cast<float4*>(Gp)     = make_float4(acc[0], acc[1], acc[2], acc[3]);
  *reinterpret_cast<float4*>(Gp + 4) = make_float4(acc[4], acc[5], acc[6], acc[7]);
}

// ---------------- Kernel D: moment accumulation in y-space (y = W1.g, no bias) ----------------
// A1[o] = sum q_t y_t[o];  A2[o] = sum a_t y_t[o]^2 + c_t y_t[o] y_{t+1}[o]
__global__ __launch_bounds__(256) void k_mom(const float* __restrict__ G, const float* __restrict__ W1,
                                             const float* __restrict__ coef, float* __restrict__ stats){
  __shared__ float sW1[CHH][CFF];
  __shared__ float sco[192];
  __shared__ float red[4][32];
  for (int i = threadIdx.x; i < CHH * CFF; i += 256) sW1[i >> 5][i & 31] = W1[i];
  if (threadIdx.x < 192) sco[threadIdx.x] = coef[threadIdx.x];
  __syncthreads();
  int t = threadIdx.x & 63;                       // lane == t  (for the shfl cross-term)
  int e = blockIdx.x * 4 + ((int)threadIdx.x >> 6); // (b,n) pair 0..1023
  int b = e >> 9, n = e & 511;
  const float* gp = G + ((size_t)((b * TT + t) * NN + n)) * CFF;
  float g[CFF];
  #pragma unroll
  for (int c = 0; c < CFF; c += 4){
    float4 v = *reinterpret_cast<const float4*>(gp + c);
    g[c] = v.x; g[c+1] = v.y; g[c+2] = v.z; g[c+3] = v.w;
  }
  float qt = sco[t], at = sco[64 + t], ct = sco[128 + t];   // ct==0 at t=63 structurally
  float v1[CHH], v2[CHH];
  #pragma unroll
  for (int o = 0; o < CHH; ++o){
    float y = 0.f;
    #pragma unroll
    for (int c = 0; c < CFF; ++c) y += sW1[o][c] * g[c];
    float yn = __shfl_down(y, 1, 64);             // y at t+1 (same b,n)
    v1[o] = qt * y;
    v2[o] = at * y * y + ct * y * yn;
  }
  #pragma unroll
  for (int o = 0; o < CHH; ++o){
    #pragma unroll
    for (int s = 32; s > 0; s >>= 1){
      v1[o] += __shfl_down(v1[o], s, 64);
      v2[o] += __shfl_down(v2[o], s, 64);
    }
  }
  int wave = threadIdx.x >> 6, lane = threadIdx.x & 63;
  if (lane == 0){
    #pragma unroll
    for (int o = 0; o < CHH; ++o){ red[wave][o] = v1[o]; red[wave][16 + o] = v2[o]; }
  }
  __syncthreads();
  if (threadIdx.x < 32){
    float v = red[0][threadIdx.x] + red[1][threadIdx.x] + red[2][threadIdx.x] + red[3][threadIdx.x];
    atomicAdd(stats + threadIdx.x, v);
  }
}

// ---------------- Kernel D2: fold BN into scale/shift ----------------
__global__ void k_fin(const float* __restrict__ gamma, const float* __restrict__ beta,
                      const float* __restrict__ b1, float* __restrict__ stats){
  int o = threadIdx.x;
  if (o < CHH){
    const float L2f = (float)(BB * (long long)LL);   // 409600
    float inv = 1.0f / L2f;
    float A1 = stats[o], A2 = stats[16 + o], bb = b1[o];
    float mu  = (A1 + L2f * bb) * inv;
    float ex2 = (A2 + 2.f * bb * A1 + L2f * bb * bb) * inv;
    float var = ex2 - mu * mu;
    float sc  = gamma[o] * (1.0f / sqrtf(var + 1e-5f));
    stats[32 + o] = sc;
    stats[48 + o] = beta[o] - mu * sc;
  }
}

// ---------------- Kernel E: h -> BN -> ReLU -> W2 -> out ----------------
__global__ __launch_bounds__(256) void k_out(const float* __restrict__ G, const float* __restrict__ W1,
                                             const float* __restrict__ b1, const float* __restrict__ W2,
                                             const float* __restrict__ b2, const float* __restrict__ stats,
                                             float* __restrict__ out){
  __shared__ float sW1[CHH][CFF];
  __shared__ float sW2[CHH][CHH];
  __shared__ float sb1[CHH], sb2[CHH], ssc[CHH], ssh[CHH];
  for (int i = threadIdx.x; i < CHH * CFF; i += 256) sW1[i >> 5][i & 31] = W1[i];
  for (int i = threadIdx.x; i < CHH * CHH; i += 256) sW2[i >> 4][i & 15] = W2[i];
  if (threadIdx.x < CHH){
    sb1[threadIdx.x] = b1[threadIdx.x];
    sb2[threadIdx.x] = b2[threadIdx.x];
    ssc[threadIdx.x] = stats[32 + threadIdx.x];
    ssh[threadIdx.x] = stats[48 + threadIdx.x];
  }
  __syncthreads();
  // XCD-contiguous block swizzle: 1600 blocks -> 8 XCDs x 200 contiguous (L2 reuse of G slabs)
  int xcd = blockIdx.x & 7, loc = blockIdx.x >> 3;
  int eb = xcd * 200 + loc;
  int li  = eb * 256 + (int)threadIdx.x;   // 0..409599
  int b   = li / LL;
  int rem = li - b * LL;
  int to  = rem >> 9;
  int n   = rem & 511;
  int i0, i1; float w;
  lerp_coeff(to, i0, i1, w);
  const float* g0 = G + ((size_t)((b * TT + i0) * NN + n)) * CFF;
  const float* g1 = G + ((size_t)((b * TT + i1) * NN + n)) * CFF;
  float g[CFF];
  #pragma unroll
  for (int c = 0; c < CFF; c += 4){
    float4 a = *reinterpret_cast<const float4*>(g0 + c);
    float4 d = *reinterpret_cast<const float4*>(g1 + c);
    g[c]   = a.x + w * (d.x - a.x);
    g[c+1] = a.y + w * (d.y - a.y);
    g[c+2] = a.z + w * (d.z - a.z);
    g[c+3] = a.w + w * (d.w - a.w);
  }
  float hr[CHH];
  #pragma unroll
  for (int o = 0; o < CHH; ++o){
    float h = sb1[o];
    #pragma unroll
    for (int c = 0; c < CFF; ++c) h += sW1[o][c] * g[c];
    hr[o] = fmaxf(h * ssc[o] + ssh[o], 0.0f);
  }
  #pragma unroll
  for (int o2 = 0; o2 < CHH; ++o2){
    float v = sb2[o2];
    #pragma unroll
    for (int o = 0; o < CHH; ++o) v += sW2[o2][o] * hr[o];
    out[((size_t)(b * CHH + o2)) * LL + rem] = v;
  }
}

extern "C" void kernel_launch(void* const* d_in, const int* in_sizes, int n_in,
                              void* d_out, int out_size, void* d_ws, size_t ws_size,
                              hipStream_t stream){
  (void)in_sizes; (void)n_in; (void)out_size; (void)ws_size;
  const float* x     = (const float*)d_in[0];
  const int*   coord = (const int*)d_in[1];
  const float* Wf    = (const float*)d_in[2];
  const float* bfv   = (const float*)d_in[3];
  const float* Wr    = (const float*)d_in[4];
  const float* br    = (const float*)d_in[5];
  const float* W1    = (const float*)d_in[6];
  const float* b1    = (const float*)d_in[7];
  const float* gamma = (const float*)d_in[8];
  const float* beta  = (const float*)d_in[9];
  const float* W2    = (const float*)d_in[10];
  const float* b2    = (const float*)d_in[11];

  float* ws    = (float*)d_ws;
  float* r     = ws;                          // 524288 f32  (2 MB)
  float* G     = ws + 524288;                 // 2097152 f32 (8 MB)
  float* stats = ws + 524288 + 2097152;       // 64 f32: [A1(16), A2(16), scale(16), shift(16)]
  float* coefp = stats + 64;                  // 192 f32: q[64], a[64], c[64]

  float* out  = (float*)d_out;                // [B,16,L] = 6,553,600 f32
  float* outR = out + (size_t)BB * CHH * LL;  // [B,1,400,64,64] = 3,276,800 f32

  hipMemsetAsync(stats, 0, 256 * sizeof(float), stream);
  k_coef  <<<2,    256, 0, stream>>>(coefp);
  k_r     <<<512,  256, 0, stream>>>(x, Wr, br, r);
  k_gather<<<1024, 256, 0, stream>>>(x, coord, Wf, bfv, G);
  k_result<<<3200, 256, 0, stream>>>(r, outR);
  k_mom   <<<256,  256, 0, stream>>>(G, W1, coefp, stats);
  k_fin   <<<1,    64,  0, stream>>>(gamma, beta, b1, stats);
  k_out   <<<1600, 256, 0, stream>>>(G, W1, b1, W2, b2, stats, out);
}

// Round 4
// 179.538 us; speedup vs baseline: 1.9228x; 1.1358x over previous
//
#include <hip/hip_runtime.h>
#include <stdint.h>

// Problem constants (from setup_inputs; harness always uses these)
#define BB   2
#define CC   32      // input channels
#define TT   64      // input T
#define HWH  4096    // H*W = 64*64
#define NN   512     // coords per batch
#define CFF  32      // feat channels
#define CHH  16      // projection channels
#define TOUT 400     // featT == orgt == 400
#define LL   (TOUT*NN)  // 204800

__device__ __forceinline__ void lerp_coeff(int to, int& i0, int& i1, float& w){
  const float step = (float)(63.0 / 399.0);   // matches python (T-1)/(out_t-1) in f32
  float pos = (float)to * step;
  i0 = (int)floorf(pos);
  if (i0 > TT - 1) i0 = TT - 1;
  i1 = i0 + 1; if (i1 > TT - 1) i1 = TT - 1;
  w = pos - (float)i0;
}

// ---------------- Kernel A: r[b][t][hw] = sum_c Wr[c]*x[b][c][t][hw] + br ----------------
// Block 0 also zeroes the 32 stats accumulators (consumed by k_mom, 3 dispatches later).
__global__ __launch_bounds__(256) void k_r(const float* __restrict__ x, const float* __restrict__ Wr,
                                           const float* __restrict__ br, float* __restrict__ r,
                                           float* __restrict__ stats){
  if (blockIdx.x == 0 && threadIdx.x < 32) stats[threadIdx.x] = 0.f;
  int tid = blockIdx.x * 256 + threadIdx.x;   // 131072 threads, 4 hw each
  int hw0 = (tid & 1023) << 2;
  int t   = (tid >> 10) & 63;
  int b   = tid >> 16;
  float br0 = br[0];
  float4 acc = make_float4(br0, br0, br0, br0);
  const float* xp = x + ((size_t)(b * CC) * TT + t) * HWH + hw0;
  #pragma unroll
  for (int c = 0; c < CC; ++c){
    float4 v = *reinterpret_cast<const float4*>(xp + (size_t)c * TT * HWH);
    float w = Wr[c];
    acc.x += w * v.x;  acc.y += w * v.y;  acc.z += w * v.z;  acc.w += w * v.w;
  }
  *reinterpret_cast<float4*>(r + ((size_t)(b * TT + t)) * HWH + hw0) = acc;
}

// ---------------- Kernel B: result = lerp_t(r) ----------------
__global__ __launch_bounds__(256) void k_result(const float* __restrict__ r, float* __restrict__ outR){
  int tid = blockIdx.x * 256 + threadIdx.x;   // 819200 threads, 4 hw each
  int hw0  = (tid & 1023) << 2;
  int rest = tid >> 10;                       // 0..799 = b*400+to
  int b  = rest >= TOUT ? 1 : 0;
  int to = rest - b * TOUT;
  int i0, i1; float w;
  lerp_coeff(to, i0, i1, w);
  float4 a = *reinterpret_cast<const float4*>(r + ((size_t)(b * TT + i0)) * HWH + hw0);
  float4 c = *reinterpret_cast<const float4*>(r + ((size_t)(b * TT + i1)) * HWH + hw0);
  float4 o;
  o.x = a.x + w * (c.x - a.x);
  o.y = a.y + w * (c.y - a.y);
  o.z = a.z + w * (c.z - a.z);
  o.w = a.w + w * (c.w - a.w);
  *reinterpret_cast<float4*>(outR + ((size_t)(b * TOUT + to)) * HWH + hw0) = o;
}

// ---------------- Kernel C: Z[b][t][n][o16] = Weff . x[b,:,t,coord] + (W1.bf + b1) ----------------
// Weff = W1(16x32) . Wf(32x32), computed once per block in LDS (cheap: 16K FMA / 256 thr).
// 4 lanes per element; each lane gathers 8 input channels, shares via __shfl, emits 4 outputs.
__global__ __launch_bounds__(256) void k_z(const float* __restrict__ x, const int* __restrict__ coord,
                                           const float* __restrict__ Wf, const float* __restrict__ bfv,
                                           const float* __restrict__ W1, const float* __restrict__ b1,
                                           float* __restrict__ Z){
  __shared__ float sWT[CC][CHH];    // Weff transposed: [c][o]
  __shared__ float scz[CHH];        // fused bias  W1.bf + b1
  for (int i = threadIdx.x; i < CHH * CC; i += 256){
    int o = i >> 5, c = i & 31;
    float v = 0.f;
    #pragma unroll
    for (int k = 0; k < CFF; ++k) v += W1[o * CFF + k] * Wf[k * CC + c];
    sWT[c][o] = v;
  }
  if (threadIdx.x < CHH){
    float v = b1[threadIdx.x];
    #pragma unroll
    for (int k = 0; k < CFF; ++k) v += W1[threadIdx.x * CFF + k] * bfv[k];
    scz[threadIdx.x] = v;
  }
  __syncthreads();
  int lane = threadIdx.x & 63;
  int sub  = threadIdx.x & 3;                        // quarter (channels in, outputs out)
  int e = blockIdx.x * 64 + ((int)threadIdx.x >> 2); // element 0..65535 = (b,t,n)
  int n = e & 511, t = (e >> 9) & 63, b = e >> 15;
  int h  = coord[(b * NN + n) * 2 + 0];
  int wq = coord[(b * NN + n) * 2 + 1];
  int hw = h * 64 + wq;
  const float* xp = x + (((size_t)(b * CC + sub * 8)) * TT + t) * HWH + hw;
  float xv[8];
  #pragma unroll
  for (int j = 0; j < 8; ++j) xv[j] = xp[(size_t)j * (TT * HWH)];
  float acc0 = scz[sub * 4], acc1 = scz[sub * 4 + 1], acc2 = scz[sub * 4 + 2], acc3 = scz[sub * 4 + 3];
  int grp = lane & ~3;
  #pragma unroll
  for (int j = 0; j < 8; ++j){
    #pragma unroll
    for (int src = 0; src < 4; ++src){
      float xc = __shfl(xv[j], grp + src, 64);   // channel c = src*8+j of this element
      int c = src * 8 + j;
      const float4 w4 = *reinterpret_cast<const float4*>(&sWT[c][sub * 4]);
      acc0 += w4.x * xc;  acc1 += w4.y * xc;  acc2 += w4.z * xc;  acc3 += w4.w * xc;
    }
  }
  *reinterpret_cast<float4*>(Z + ((size_t)((b * TT + t) * NN + n)) * CHH + sub * 4)
      = make_float4(acc0, acc1, acc2, acc3);
}

// ---------------- Kernel D: moment accumulation: h_to = lerp(Z), need sum h, sum h^2 ----------------
// A1[o] = sum_t q_t z_t[o];  A2[o] = sum_t a_t z_t[o]^2 + c_t z_t[o] z_{t+1}[o]
// q/a/c (lerp moment coefficients over the 400 outputs) computed per block in LDS.
__global__ __launch_bounds__(256) void k_mom(const float* __restrict__ Z, float* __restrict__ stats){
  __shared__ float sco[192];        // q[64], a[64], c[64]
  __shared__ float red[4][32];
  if (threadIdx.x < 192) sco[threadIdx.x] = 0.f;
  __syncthreads();
  for (int to = threadIdx.x; to < TOUT; to += 256){
    int i0, i1; float w;
    lerp_coeff(to, i0, i1, w);
    if (i1 == i0){
      atomicAdd(&sco[i0], 1.f);  atomicAdd(&sco[64 + i0], 1.f);
    } else {
      float u = 1.f - w;
      atomicAdd(&sco[i0], u);        atomicAdd(&sco[64 + i0], u * u);
      atomicAdd(&sco[i1], w);        atomicAdd(&sco[64 + i1], w * w);
      atomicAdd(&sco[128 + i0], 2.f * w * u);
    }
  }
  __syncthreads();
  int t = threadIdx.x & 63;                         // lane == t (for the shfl cross-term)
  int e = blockIdx.x * 4 + ((int)threadIdx.x >> 6); // (b,n) 0..1023
  int b = e >> 9, n = e & 511;
  const float* zp = Z + ((size_t)((b * TT + t) * NN + n)) * CHH;
  float z[CHH];
  #pragma unroll
  for (int c = 0; c < CHH; c += 4){
    float4 v = *reinterpret_cast<const float4*>(zp + c);
    z[c] = v.x; z[c+1] = v.y; z[c+2] = v.z; z[c+3] = v.w;
  }
  float qt = sco[t], at = sco[64 + t], ct = sco[128 + t];   // ct==0 at t=63 structurally
  float v1[CHH], v2[CHH];
  #pragma unroll
  for (int o = 0; o < CHH; ++o){
    float zn = __shfl_down(z[o], 1, 64);            // z at t+1 (same b,n)
    v1[o] = qt * z[o];
    v2[o] = at * z[o] * z[o] + ct * z[o] * zn;
  }
  #pragma unroll
  for (int o = 0; o < CHH; ++o){
    #pragma unroll
    for (int s = 32; s > 0; s >>= 1){
      v1[o] += __shfl_down(v1[o], s, 64);
      v2[o] += __shfl_down(v2[o], s, 64);
    }
  }
  int wave = threadIdx.x >> 6, lane = threadIdx.x & 63;
  if (lane == 0){
    #pragma unroll
    for (int o = 0; o < CHH; ++o){ red[wave][o] = v1[o]; red[wave][16 + o] = v2[o]; }
  }
  __syncthreads();
  if (threadIdx.x < 32){
    float v = red[0][threadIdx.x] + red[1][threadIdx.x] + red[2][threadIdx.x] + red[3][threadIdx.x];
    atomicAdd(stats + threadIdx.x, v);
  }
}

// ---------------- Kernel E: h = lerp(Z) -> BN -> ReLU -> W2 -> out ----------------
// BN scale/shift derived from stats per block (replaces k_fin dispatch).
__global__ __launch_bounds__(256) void k_out(const float* __restrict__ Z, const float* __restrict__ W2,
                                             const float* __restrict__ b2, const float* __restrict__ gamma,
                                             const float* __restrict__ beta, const float* __restrict__ stats,
                                             float* __restrict__ out){
  __shared__ float sW2[CHH][CHH];
  __shared__ float sb2[CHH], ssc[CHH], ssh[CHH];
  for (int i = threadIdx.x; i < CHH * CHH; i += 256) sW2[i >> 4][i & 15] = W2[i];
  if (threadIdx.x < CHH){
    int o = threadIdx.x;
    const float inv = 1.0f / (float)(BB * (long long)LL);   // 1/409600
    float mu  = stats[o] * inv;
    float var = stats[16 + o] * inv - mu * mu;
    float sc  = gamma[o] * (1.0f / sqrtf(var + 1e-5f));
    ssc[o] = sc;
    ssh[o] = beta[o] - mu * sc;
    sb2[o] = b2[o];
  }
  __syncthreads();
  // XCD-contiguous block swizzle: 1600 blocks -> 8 XCDs x 200 contiguous (L2 reuse of Z slabs)
  int xcd = blockIdx.x & 7, loc = blockIdx.x >> 3;
  int eb = xcd * 200 + loc;
  int li  = eb * 256 + (int)threadIdx.x;   // 0..409599
  int b   = li / LL;
  int rem = li - b * LL;
  int to  = rem >> 9;
  int n   = rem & 511;
  int i0, i1; float w;
  lerp_coeff(to, i0, i1, w);
  const float* z0 = Z + ((size_t)((b * TT + i0) * NN + n)) * CHH;
  const float* z1 = Z + ((size_t)((b * TT + i1) * NN + n)) * CHH;
  float hr[CHH];
  #pragma unroll
  for (int c = 0; c < CHH; c += 4){
    float4 a = *reinterpret_cast<const float4*>(z0 + c);
    float4 d = *reinterpret_cast<const float4*>(z1 + c);
    float h0 = a.x + w * (d.x - a.x);
    float h1 = a.y + w * (d.y - a.y);
    float h2 = a.z + w * (d.z - a.z);
    float h3 = a.w + w * (d.w - a.w);
    hr[c]   = fmaxf(h0 * ssc[c]   + ssh[c],   0.0f);
    hr[c+1] = fmaxf(h1 * ssc[c+1] + ssh[c+1], 0.0f);
    hr[c+2] = fmaxf(h2 * ssc[c+2] + ssh[c+2], 0.0f);
    hr[c+3] = fmaxf(h3 * ssc[c+3] + ssh[c+3], 0.0f);
  }
  #pragma unroll
  for (int o2 = 0; o2 < CHH; ++o2){
    float v = sb2[o2];
    #pragma unroll
    for (int o = 0; o < CHH; ++o) v += sW2[o2][o] * hr[o];
    out[((size_t)(b * CHH + o2)) * LL + rem] = v;
  }
}

extern "C" void kernel_launch(void* const* d_in, const int* in_sizes, int n_in,
                              void* d_out, int out_size, void* d_ws, size_t ws_size,
                              hipStream_t stream){
  (void)in_sizes; (void)n_in; (void)out_size; (void)ws_size;
  const float* x     = (const float*)d_in[0];
  const int*   coord = (const int*)d_in[1];
  const float* Wf    = (const float*)d_in[2];
  const float* bfv   = (const float*)d_in[3];
  const float* Wr    = (const float*)d_in[4];
  const float* br    = (const float*)d_in[5];
  const float* W1    = (const float*)d_in[6];
  const float* b1    = (const float*)d_in[7];
  const float* gamma = (const float*)d_in[8];
  const float* beta  = (const float*)d_in[9];
  const float* W2    = (const float*)d_in[10];
  const float* b2    = (const float*)d_in[11];

  float* ws    = (float*)d_ws;
  float* r     = ws;                          // 524288 f32  (2 MB)
  float* Z     = ws + 524288;                 // 1048576 f32 (4 MB)
  float* stats = ws + 524288 + 1048576;       // 32 f32: [A1(16), A2(16)]

  float* out  = (float*)d_out;                // [B,16,L] = 6,553,600 f32
  float* outR = out + (size_t)BB * CHH * LL;  // [B,1,400,64,64] = 3,276,800 f32

  k_r     <<<512,  256, 0, stream>>>(x, Wr, br, r, stats);
  k_z     <<<1024, 256, 0, stream>>>(x, coord, Wf, bfv, W1, b1, Z);
  k_result<<<3200, 256, 0, stream>>>(r, outR);
  k_mom   <<<256,  256, 0, stream>>>(Z, stats);
  k_out   <<<1600, 256, 0, stream>>>(Z, W2, b2, gamma, beta, stats, out);
}